// Round 8
// baseline (250.672 us; speedup 1.0000x reference)
//
#include <hip/hip_runtime.h>
#include <math.h>

// Problem constants (b=8, c=2048, e=64, h=8)
#define NTOK 16384
#define EDIM 64
#define HHE  512   // h*e

typedef _Float16 half8 __attribute__((ext_vector_type(8)));
typedef float    floatx4 __attribute__((ext_vector_type(4)));

__device__ __forceinline__ half8 cvt8(const float4 a, const float4 b) {
    half8 h;
    h[0] = (_Float16)a.x; h[1] = (_Float16)a.y;
    h[2] = (_Float16)a.z; h[3] = (_Float16)a.w;
    h[4] = (_Float16)b.x; h[5] = (_Float16)b.y;
    h[6] = (_Float16)b.z; h[7] = (_Float16)b.w;
    return h;
}

// ---------------------------------------------------------------------------
// Kernel 1: q/k/v = x @ W^T + b   (M=16384, N=512 per matrix, K=64) — MFMA
// R7 version, unchanged. Held constant.
// ---------------------------------------------------------------------------
__global__ __launch_bounds__(256) void qkv_kernel(
    const float* __restrict__ x,
    const float* __restrict__ Wk, const float* __restrict__ bk,
    const float* __restrict__ Wq, const float* __restrict__ bq,
    const float* __restrict__ Wv, const float* __restrict__ bv,
    float* __restrict__ qb, float* __restrict__ kb, float* __restrict__ vb)
{
    const int tid  = threadIdx.x;
    const int lane = tid & 63;
    const int wv   = tid >> 6;             // wave 0..3
    const int z    = blockIdx.z;

    const float* W; const float* bias; float* outp;
    if      (z == 0) { W = Wk; bias = bk; outp = kb; }
    else if (z == 1) { W = Wq; bias = bq; outp = qb; }
    else             { W = Wv; bias = bv; outp = vb; }

    const int tok0 = blockIdx.x * 64 + wv * 16;   // this wave's 16 tokens
    const int col0 = blockIdx.y * 128;            // this block's 128 cols

    const int m    = lane & 15;            // A row (tok) / B row (col) / C col
    const int quad = lane >> 4;            // k-quad: k = quad*8 + j

    floatx4 acc[8];
    #pragma unroll
    for (int ct = 0; ct < 8; ++ct) acc[ct] = (floatx4){0.f, 0.f, 0.f, 0.f};

    const float* xrow = x + (size_t)(tok0 + m) * EDIM + quad * 8;

    #pragma unroll
    for (int kc = 0; kc < 2; ++kc) {       // K=64 in two 32-chunks
        const float4 xa = *(const float4*)(xrow + kc * 32);
        const float4 xb = *(const float4*)(xrow + kc * 32 + 4);
        const half8 af = cvt8(xa, xb);
        #pragma unroll
        for (int ct = 0; ct < 8; ++ct) {
            const float* wrow =
                W + (size_t)(col0 + ct * 16 + m) * EDIM + quad * 8 + kc * 32;
            const float4 wa = *(const float4*)(wrow);
            const float4 wb = *(const float4*)(wrow + 4);
            const half8 bf = cvt8(wa, wb);
            acc[ct] = __builtin_amdgcn_mfma_f32_16x16x32_f16(af, bf, acc[ct], 0, 0, 0);
        }
    }

    // epilogue: bias + store. C/D: col = m, row = quad*4 + r.
    #pragma unroll
    for (int ct = 0; ct < 8; ++ct) {
        const int col = col0 + ct * 16 + m;
        const float bn = bias[col];
        #pragma unroll
        for (int r = 0; r < 4; ++r) {
            const int tok = tok0 + quad * 4 + r;
            outp[(size_t)tok * HHE + col] = acc[ct][r] + bn;
        }
    }
}

// ---------------------------------------------------------------------------
// Kernel 2: per-token scores -> entmax_bisect -> att @ v   — LDS-FREE
// One wave per token. k/v rows are wave-uniform -> read through uniform
// pointers (readfirstlane'd wave id) so the compiler scalarizes them to
// s_load feeding v_fma's SGPR operand. No LDS, no barriers, no DS-pipe
// traffic. Unlike R6-qkv's serialized scalar loads, the SMEM loads here
// happen once per wave (dot) + once (av) with 10 pure-VALU bisection
// passes between them — resident waves hide the latency.
// 6 bisect + 3 guarded Newton: e0 = 0.875*2^-6 = 0.0137 < 1/32, Newton
// e' <= 32 e^2 -> e3 <= 4.2e-5 -> p-err ~8e-5 (vs 4.28e-2 threshold).
// ---------------------------------------------------------------------------
__device__ __forceinline__ float clamp01(float z) {
    return __builtin_amdgcn_fmed3f(z, 0.0f, 1.0f);   // v_med3_f32
}
__device__ __forceinline__ float pgen(float z, float inv) {
    return z > 0.0f ? exp2f(inv * log2f(fmaxf(z, 1e-30f))) : 0.0f;
}

__global__ __launch_bounds__(256) void attn_kernel(
    float* qb,                    // read q, then write res (alias)
    const float* __restrict__ kb, const float* __restrict__ vb,
    const float* alpha_p)
{
    const int lane = threadIdx.x & 63;
    const int w    = __builtin_amdgcn_readfirstlane(threadIdx.x >> 6); // uniform
    const int tok  = blockIdx.x * 4 + w;                               // uniform

    const float alpha = alpha_p[0];
    const float am1   = alpha - 1.0f;

    const float* __restrict__ qp = qb + (size_t)tok * HHE;
    const float* __restrict__ kp = kb + (size_t)tok * HHE;  // uniform addr
    const float* __restrict__ vp = vb + (size_t)tok * HHE;  // uniform addr

    float qr[8];
    #pragma unroll
    for (int h = 0; h < 8; ++h) qr[h] = qp[h * 64 + lane];  // coalesced

    // dot row: row[j] = sum_h q[h][lane] * k[h][j]; k via scalar loads
    float row[64];
    #pragma unroll
    for (int j = 0; j < 64; ++j) row[j] = 0.0f;
    #pragma unroll
    for (int h = 0; h < 8; ++h) {
        float kv[64];                      // wave-uniform -> SGPR chunks
        #pragma unroll
        for (int j = 0; j < 64; ++j) kv[j] = kp[h * 64 + j];
        const float qh = qr[h];
        #pragma unroll
        for (int j = 0; j < 64; ++j) row[j] = fmaf(qh, kv[j], row[j]);
    }

    // Xa = dot/sqrt(e) * (alpha-1);  1/8 and am1 fold exactly (pow-of-2)
    const float scale = am1 * 0.125f;
    #pragma unroll
    for (int j = 0; j < 64; ++j) row[j] *= scale;

    float mx = row[0];
    #pragma unroll
    for (int j = 1; j < 64; ++j) mx = fmaxf(mx, row[j]);

    float tau_lo = mx - 1.0f;                         // _gp(1, alpha) = 1
    const float tau_hi = mx - exp2f(-6.0f * am1);     // (1/64)^am1
    float dm = tau_hi - tau_lo;
    float inv_sum;
    float pfin = 0.0f;                                // final tau holder

    if (am1 == 0.5f) {
        // alpha = 1.5: p(z) = max(z,0)^2; z <= 1 always (tau >= mx-1).
        // 6 bisection steps, f >= 0 test (f_lo >= 0 provably; one-hot-safe).
        #pragma unroll
        for (int it = 0; it < 6; ++it) {
            dm *= 0.5f;
            const float tau_m = tau_lo + dm;
            float f0 = -1.0f, f1 = 0.0f, f2 = 0.0f, f3 = 0.0f;
            #pragma unroll
            for (int j = 0; j < 64; j += 4) {
                const float a0 = clamp01(row[j+0] - tau_m);
                const float a1 = clamp01(row[j+1] - tau_m);
                const float a2 = clamp01(row[j+2] - tau_m);
                const float a3 = clamp01(row[j+3] - tau_m);
                f0 = fmaf(a0, a0, f0); f1 = fmaf(a1, a1, f1);
                f2 = fmaf(a2, a2, f2); f3 = fmaf(a3, a3, f3);
            }
            const float f = (f0 + f1) + (f2 + f3);
            tau_lo = (f >= 0.0f) ? tau_m : tau_lo;
        }
        // 3 guarded Newton steps (tau += max(f,0)/(2s); never moves if f<0)
        float tau = tau_lo;
        #pragma unroll
        for (int it = 0; it < 3; ++it) {
            float f0 = -1.0f, f1 = 0.0f, f2 = 0.0f, f3 = 0.0f;
            float s0 = 0.0f, s1 = 0.0f, s2 = 0.0f, s3 = 0.0f;
            #pragma unroll
            for (int j = 0; j < 64; j += 4) {
                const float a0 = clamp01(row[j+0] - tau);
                const float a1 = clamp01(row[j+1] - tau);
                const float a2 = clamp01(row[j+2] - tau);
                const float a3 = clamp01(row[j+3] - tau);
                f0 = fmaf(a0, a0, f0); f1 = fmaf(a1, a1, f1);
                f2 = fmaf(a2, a2, f2); f3 = fmaf(a3, a3, f3);
                s0 += a0; s1 += a1; s2 += a2; s3 += a3;
            }
            const float f = (f0 + f1) + (f2 + f3);
            const float s = ((s0 + s1) + (s2 + s3)) + 1e-20f;  // s >= 1/8 anyway
            tau = tau + fmaxf(f, 0.0f) / (s + s);
        }
        // final p (unnormalized) + sum; normalization folded into av epilogue
        float s0 = 0.0f, s1 = 0.0f;
        #pragma unroll
        for (int j = 0; j < 64; j += 2) {
            float a0 = clamp01(row[j+0] - tau);
            float a1 = clamp01(row[j+1] - tau);
            a0 *= a0; a1 *= a1;
            row[j+0] = a0; row[j+1] = a1;
            s0 += a0; s1 += a1;
        }
        inv_sum = 1.0f / (s0 + s1);
        pfin = tau;
        (void)pfin;
    } else {
        // faithful general-alpha path (unused for this problem's alpha=1.5)
        const float inv = 1.0f / am1;
        float tau_m = tau_lo;
        float f_lo = -1.0f;
        #pragma unroll
        for (int j = 0; j < 64; ++j) f_lo += pgen(row[j] - tau_lo, inv);
        for (int it = 0; it < 30; ++it) {
            dm *= 0.5f;
            tau_m = tau_lo + dm;
            float f = -1.0f;
            #pragma unroll
            for (int j = 0; j < 64; ++j) f += pgen(row[j] - tau_m, inv);
            tau_lo = (f * f_lo >= 0.0f) ? tau_m : tau_lo;
        }
        float s = 0.0f;
        #pragma unroll
        for (int j = 0; j < 64; ++j) {
            const float pm = pgen(row[j] - tau_m, inv);
            row[j] = pm;
            s += pm;
        }
        inv_sum = 1.0f / s;
    }

    // res[h][lane] = inv_sum * sum_j p[lane][j] * v[h][j]; v via scalar loads
    float acc[8];
    #pragma unroll
    for (int h = 0; h < 8; ++h) acc[h] = 0.0f;
    #pragma unroll
    for (int h = 0; h < 8; ++h) {
        float vv[64];                      // wave-uniform -> SGPR chunks
        #pragma unroll
        for (int j = 0; j < 64; ++j) vv[j] = vp[h * 64 + j];
        float a0 = 0.0f, a1 = 0.0f, a2 = 0.0f, a3 = 0.0f;
        #pragma unroll
        for (int j = 0; j < 64; j += 4) {
            a0 = fmaf(row[j+0], vv[j+0], a0);
            a1 = fmaf(row[j+1], vv[j+1], a1);
            a2 = fmaf(row[j+2], vv[j+2], a2);
            a3 = fmaf(row[j+3], vv[j+3], a3);
        }
        acc[h] = (a0 + a1) + (a2 + a3);
    }
    float* rp = qb + (size_t)tok * HHE;   // res overwrites q (safe: own wave only)
    #pragma unroll
    for (int h = 0; h < 8; ++h) rp[h * 64 + lane] = acc[h] * inv_sum;
}

// ---------------------------------------------------------------------------
// Kernel 3: out = res @ Wu^T + bu   (M=16384, N=64, K=512)
// R5 version, unchanged (k-outer LDS GEMM, conflict-free). Held constant.
// ---------------------------------------------------------------------------
__global__ __launch_bounds__(256) void out_kernel(
    const float* __restrict__ resb, const float* __restrict__ Wu,
    const float* __restrict__ bu, float* __restrict__ out)
{
    __shared__ float rT[64 * 68];        // [kk][tok]  17.4 KB
    __shared__ float wT[64 * 68];        // [kk][m]    17.4 KB

    const int tid  = threadIdx.x;
    const int tok0 = blockIdx.x * 64;

    const int t    = tid >> 2;           // 0..63 (staging: token row / Wu row)
    const int kq2  = tid & 3;            // 0..3
    const int tokq = tid >> 4;           // 0..15 (compute: 4-token group)
    const int mq   = tid & 15;           // 0..15 (compute: 4-col group)

    float acc[4][4];
    #pragma unroll
    for (int a = 0; a < 4; ++a)
        #pragma unroll
        for (int b = 0; b < 4; ++b) acc[a][b] = 0.0f;

    const float4* rg = (const float4*)(resb + (size_t)(tok0 + t) * HHE);
    const float4* wg = (const float4*)(Wu   + (size_t)t * HHE);

    for (int kc = 0; kc < 8; ++kc) {
        // ---- stage res & Wu chunks transposed into LDS
        #pragma unroll
        for (int rep = 0; rep < 4; ++rep) {
            const int kq = rep * 4 + kq2;            // 0..15 within chunk
            const float4 rv = rg[kc * 16 + kq];
            rT[(kq * 4 + 0) * 68 + t] = rv.x;
            rT[(kq * 4 + 1) * 68 + t] = rv.y;
            rT[(kq * 4 + 2) * 68 + t] = rv.z;
            rT[(kq * 4 + 3) * 68 + t] = rv.w;
            const float4 wv = wg[kc * 16 + kq];
            wT[(kq * 4 + 0) * 68 + t] = wv.x;
            wT[(kq * 4 + 1) * 68 + t] = wv.y;
            wT[(kq * 4 + 2) * 68 + t] = wv.z;
            wT[(kq * 4 + 3) * 68 + t] = wv.w;
        }
        __syncthreads();

        // ---- compute: per kk, 2 x ds_read_b128 + 16 fma
        #pragma unroll 4
        for (int kk = 0; kk < 64; ++kk) {
            const float4 a4 = *(const float4*)&rT[kk * 68 + tokq * 4];
            const float4 b4 = *(const float4*)&wT[kk * 68 + mq * 4];
            const float ar[4] = {a4.x, a4.y, a4.z, a4.w};
            const float br[4] = {b4.x, b4.y, b4.z, b4.w};
            #pragma unroll
            for (int a = 0; a < 4; ++a)
                #pragma unroll
                for (int b = 0; b < 4; ++b)
                    acc[a][b] = fmaf(ar[a], br[b], acc[a][b]);
        }
        __syncthreads();                 // LDS reused next chunk
    }

    const float4 b4 = ((const float4*)bu)[mq];
    #pragma unroll
    for (int a = 0; a < 4; ++a) {
        float4 o;
        o.x = acc[a][0] + b4.x;
        o.y = acc[a][1] + b4.y;
        o.z = acc[a][2] + b4.z;
        o.w = acc[a][3] + b4.w;
        *(float4*)&out[(size_t)(tok0 + tokq * 4 + a) * 64 + mq * 4] = o;
    }
}

// ---------------------------------------------------------------------------
extern "C" void kernel_launch(void* const* d_in, const int* in_sizes, int n_in,
                              void* d_out, int out_size, void* d_ws, size_t ws_size,
                              hipStream_t stream)
{
    const float* x     = (const float*)d_in[0];
    const float* alpha = (const float*)d_in[1];
    const float* Wk    = (const float*)d_in[2];
    const float* bk    = (const float*)d_in[3];
    const float* Wq    = (const float*)d_in[4];
    const float* bq    = (const float*)d_in[5];
    const float* Wv    = (const float*)d_in[6];
    const float* bv    = (const float*)d_in[7];
    const float* Wu    = (const float*)d_in[8];
    const float* bu    = (const float*)d_in[9];
    float* out = (float*)d_out;

    float* ws = (float*)d_ws;
    float* qb = ws;                                  // res aliases q
    float* kb = ws + (size_t)NTOK * HHE;
    float* vb = ws + 2 * (size_t)NTOK * HHE;         // total 96 MB

    qkv_kernel<<<dim3(NTOK / 64, 4, 3), 256, 0, stream>>>(
        x, Wk, bk, Wq, bq, Wv, bv, qb, kb, vb);
    attn_kernel<<<NTOK / 4, 256, 0, stream>>>(qb, kb, vb, alpha);
    out_kernel<<<NTOK / 64, 256, 0, stream>>>(qb, Wu, bu, out);
}

// Round 10
// 218.460 us; speedup vs baseline: 1.1474x; 1.1474x over previous
//
#include <hip/hip_runtime.h>
#include <math.h>

// Problem constants (b=8, c=2048, e=64, h=8)
#define NTOK 16384
#define EDIM 64
#define HHE  512   // h*e

typedef _Float16 half8 __attribute__((ext_vector_type(8)));   // MFMA operand type
typedef __fp16   half2v __attribute__((ext_vector_type(2)));  // builtin V2h type
typedef float    floatx4 __attribute__((ext_vector_type(4)));

__device__ __forceinline__ half8 cvt8(const float4 a, const float4 b) {
    half8 h;
    h[0] = (_Float16)a.x; h[1] = (_Float16)a.y;
    h[2] = (_Float16)a.z; h[3] = (_Float16)a.w;
    h[4] = (_Float16)b.x; h[5] = (_Float16)b.y;
    h[6] = (_Float16)b.z; h[7] = (_Float16)b.w;
    return h;
}

// fp32 += half2 . half2 (v_dot2_f32_f16); float fallback if builtin missing
__device__ __forceinline__ float dot2(half2v a, half2v b, float c) {
#if __has_builtin(__builtin_amdgcn_fdot2)
    return __builtin_amdgcn_fdot2(a, b, c, false);
#else
    return fmaf((float)a[0], (float)b[0], fmaf((float)a[1], (float)b[1], c));
#endif
}
__device__ __forceinline__ half2v pk(float x, float y) {
    return __builtin_amdgcn_cvt_pkrtz(x, y);   // v_cvt_pkrtz_f16_f32 (V2h)
}

// ---------------------------------------------------------------------------
// Kernel 1: q/k/v = x @ W^T + b   (M=16384, N=512 per matrix, K=64) — MFMA
// R7 version, unchanged. Held constant.
// ---------------------------------------------------------------------------
__global__ __launch_bounds__(256) void qkv_kernel(
    const float* __restrict__ x,
    const float* __restrict__ Wk, const float* __restrict__ bk,
    const float* __restrict__ Wq, const float* __restrict__ bq,
    const float* __restrict__ Wv, const float* __restrict__ bv,
    float* __restrict__ qb, float* __restrict__ kb, float* __restrict__ vb)
{
    const int tid  = threadIdx.x;
    const int lane = tid & 63;
    const int wv   = tid >> 6;             // wave 0..3
    const int z    = blockIdx.z;

    const float* W; const float* bias; float* outp;
    if      (z == 0) { W = Wk; bias = bk; outp = kb; }
    else if (z == 1) { W = Wq; bias = bq; outp = qb; }
    else             { W = Wv; bias = bv; outp = vb; }

    const int tok0 = blockIdx.x * 64 + wv * 16;   // this wave's 16 tokens
    const int col0 = blockIdx.y * 128;            // this block's 128 cols

    const int m    = lane & 15;            // A row (tok) / B row (col) / C col
    const int quad = lane >> 4;            // k-quad: k = quad*8 + j

    floatx4 acc[8];
    #pragma unroll
    for (int ct = 0; ct < 8; ++ct) acc[ct] = (floatx4){0.f, 0.f, 0.f, 0.f};

    const float* xrow = x + (size_t)(tok0 + m) * EDIM + quad * 8;

    #pragma unroll
    for (int kc = 0; kc < 2; ++kc) {       // K=64 in two 32-chunks
        const float4 xa = *(const float4*)(xrow + kc * 32);
        const float4 xb = *(const float4*)(xrow + kc * 32 + 4);
        const half8 af = cvt8(xa, xb);
        #pragma unroll
        for (int ct = 0; ct < 8; ++ct) {
            const float* wrow =
                W + (size_t)(col0 + ct * 16 + m) * EDIM + quad * 8 + kc * 32;
            const float4 wa = *(const float4*)(wrow);
            const float4 wb = *(const float4*)(wrow + 4);
            const half8 bf = cvt8(wa, wb);
            acc[ct] = __builtin_amdgcn_mfma_f32_16x16x32_f16(af, bf, acc[ct], 0, 0, 0);
        }
    }

    // epilogue: bias + store. C/D: col = m, row = quad*4 + r.
    #pragma unroll
    for (int ct = 0; ct < 8; ++ct) {
        const int col = col0 + ct * 16 + m;
        const float bn = bias[col];
        #pragma unroll
        for (int r = 0; r < 4; ++r) {
            const int tok = tok0 + quad * 4 + r;
            outp[(size_t)tok * HHE + col] = acc[ct][r] + bn;
        }
    }
}

// ---------------------------------------------------------------------------
// Kernel 2: per-token scores -> entmax_bisect -> att @ v  — fp16 LDS + dot2
// One wave per token (lane = score row, bisection pure per-lane fp32 —
// byte-identical logic to R8's proven 6-bisect + 3-guarded-Newton).
// DS-diet vs R7 (R7 was DS-pipe-bound: ~256 b128/wave through the per-CU
// DS pipe ~ 80 µs at 64 waves/CU):
//   k staged transposed as kT[j][4xhalf2] (16B rows) -> dot reads ONE
//   broadcast b128 per j (64 total) + 4 v_dot2_f32_f16 (fp32 accum).
//   v staged as v16[h][j-pairs] -> av reads 64 b128 + 256 dot2 on fp16 p.
//   Staging: 1 ds_write_b128 + 4 ds_write_b32 per lane; per-wave-private
//   LDS slices -> NO __syncthreads anywhere (wave-internal lgkmcnt only).
// fp16 rounding adds ~1e-3 rel to scores/p (threshold 4.28e-2; qkv fp16
// already dominates at 0.0078).
// ---------------------------------------------------------------------------
__device__ __forceinline__ float clamp01(float z) {
    return __builtin_amdgcn_fmed3f(z, 0.0f, 1.0f);   // v_med3_f32
}
__device__ __forceinline__ float pgen(float z, float inv) {
    return z > 0.0f ? exp2f(inv * log2f(fmaxf(z, 1e-30f))) : 0.0f;
}

__global__ __launch_bounds__(256) void attn_kernel(
    float* qb,                    // read q, then write res (alias)
    const float* __restrict__ kb, const float* __restrict__ vb,
    const float* alpha_p)
{
    // per-wave private slices (1 KB each): no cross-wave sharing, no barrier
    __shared__ __align__(16) half2v kT[4][64 * 4];   // [w][j*4 + hpair]
    __shared__ __align__(16) half2v v16[4][8 * 32];  // [w][h*32 + jpair]

    const int lane = threadIdx.x & 63;
    const int w    = threadIdx.x >> 6;
    const int tok  = blockIdx.x * 4 + w;

    const float alpha = alpha_p[0];
    const float am1   = alpha - 1.0f;

    const float* __restrict__ qp = qb + (size_t)tok * HHE;
    const float* __restrict__ kp = kb + (size_t)tok * HHE;
    const float* __restrict__ vp = vb + (size_t)tok * HHE;

    // ---- load q (per-lane), stage k transposed + v packed (coalesced)
    float qr[8];
    #pragma unroll
    for (int h = 0; h < 8; ++h) qr[h] = qp[h * 64 + lane];
    half2v q2[4];
    #pragma unroll
    for (int i = 0; i < 4; ++i) q2[i] = pk(qr[2 * i], qr[2 * i + 1]);

    {   // k: lane j=lane reads k[h][j] for all h, packs h-pairs, one b128 write
        float kv[8];
        #pragma unroll
        for (int h = 0; h < 8; ++h) kv[h] = kp[h * 64 + lane];
        union { half8 h8; half2v h2[4]; } u;
        #pragma unroll
        for (int i = 0; i < 4; ++i) u.h2[i] = pk(kv[2 * i], kv[2 * i + 1]);
        *(half8*)&kT[w][lane * 4] = u.h8;
    }
    {   // v: lane (jp = lane&31, hh = lane>>5) stages 4 h rows of j-pair jp
        const int jp = lane & 31;
        const int hh = lane >> 5;
        #pragma unroll
        for (int hi = 0; hi < 4; ++hi) {
            const int h = hh * 4 + hi;
            const float2 vv = *(const float2*)&vp[h * 64 + 2 * jp];
            v16[w][h * 32 + jp] = pk(vv.x, vv.y);
        }
    }
    // wave-private LDS: compiler's lgkmcnt ordering suffices (no barrier)

    // ---- dot row: row[j] = sum_h q[h][lane] * k[h][j]  (4 dot2 per j)
    float row[64];
    #pragma unroll
    for (int j = 0; j < 64; ++j) {
        union { half8 h8; half2v h2[4]; } u;
        u.h8 = *(const half8*)&kT[w][j * 4];        // broadcast b128
        float d = dot2(q2[0], u.h2[0], 0.0f);
        d = dot2(q2[1], u.h2[1], d);
        d = dot2(q2[2], u.h2[2], d);
        d = dot2(q2[3], u.h2[3], d);
        row[j] = d;
    }

    // Xa = dot/sqrt(e) * (alpha-1);  1/8 and am1 fold exactly (pow-of-2)
    const float scale = am1 * 0.125f;
    #pragma unroll
    for (int j = 0; j < 64; ++j) row[j] *= scale;

    float mx = row[0];
    #pragma unroll
    for (int j = 1; j < 64; ++j) mx = fmaxf(mx, row[j]);

    float tau_lo = mx - 1.0f;                         // _gp(1, alpha) = 1
    const float tau_hi = mx - exp2f(-6.0f * am1);     // (1/64)^am1
    float dm = tau_hi - tau_lo;
    float inv_sum;

    if (am1 == 0.5f) {
        // alpha = 1.5: p(z) = max(z,0)^2; z <= 1 always (tau >= mx-1).
        // 6 bisection steps, f >= 0 test (f_lo >= 0 provably; one-hot-safe).
        #pragma unroll
        for (int it = 0; it < 6; ++it) {
            dm *= 0.5f;
            const float tau_m = tau_lo + dm;
            float f0 = -1.0f, f1 = 0.0f, f2 = 0.0f, f3 = 0.0f;
            #pragma unroll
            for (int j = 0; j < 64; j += 4) {
                const float a0 = clamp01(row[j+0] - tau_m);
                const float a1 = clamp01(row[j+1] - tau_m);
                const float a2 = clamp01(row[j+2] - tau_m);
                const float a3 = clamp01(row[j+3] - tau_m);
                f0 = fmaf(a0, a0, f0); f1 = fmaf(a1, a1, f1);
                f2 = fmaf(a2, a2, f2); f3 = fmaf(a3, a3, f3);
            }
            const float f = (f0 + f1) + (f2 + f3);
            tau_lo = (f >= 0.0f) ? tau_m : tau_lo;
        }
        // 3 guarded Newton steps (tau += max(f,0)/(2s); never moves if f<0)
        float tau = tau_lo;
        #pragma unroll
        for (int it = 0; it < 3; ++it) {
            float f0 = -1.0f, f1 = 0.0f, f2 = 0.0f, f3 = 0.0f;
            float s0 = 0.0f, s1 = 0.0f, s2 = 0.0f, s3 = 0.0f;
            #pragma unroll
            for (int j = 0; j < 64; j += 4) {
                const float a0 = clamp01(row[j+0] - tau);
                const float a1 = clamp01(row[j+1] - tau);
                const float a2 = clamp01(row[j+2] - tau);
                const float a3 = clamp01(row[j+3] - tau);
                f0 = fmaf(a0, a0, f0); f1 = fmaf(a1, a1, f1);
                f2 = fmaf(a2, a2, f2); f3 = fmaf(a3, a3, f3);
                s0 += a0; s1 += a1; s2 += a2; s3 += a3;
            }
            const float f = (f0 + f1) + (f2 + f3);
            const float s = ((s0 + s1) + (s2 + s3)) + 1e-20f;  // s >= 1/8 anyway
            tau = tau + fmaxf(f, 0.0f) / (s + s);
        }
        // final p (unnormalized) + sum; normalization folded into av epilogue
        float s0 = 0.0f, s1 = 0.0f;
        #pragma unroll
        for (int j = 0; j < 64; j += 2) {
            float a0 = clamp01(row[j+0] - tau);
            float a1 = clamp01(row[j+1] - tau);
            a0 *= a0; a1 *= a1;
            row[j+0] = a0; row[j+1] = a1;
            s0 += a0; s1 += a1;
        }
        inv_sum = 1.0f / (s0 + s1);
    } else {
        // faithful general-alpha path (unused for this problem's alpha=1.5)
        const float inv = 1.0f / am1;
        float tau_m = tau_lo;
        float f_lo = -1.0f;
        #pragma unroll
        for (int j = 0; j < 64; ++j) f_lo += pgen(row[j] - tau_lo, inv);
        for (int it = 0; it < 30; ++it) {
            dm *= 0.5f;
            tau_m = tau_lo + dm;
            float f = -1.0f;
            #pragma unroll
            for (int j = 0; j < 64; ++j) f += pgen(row[j] - tau_m, inv);
            tau_lo = (f * f_lo >= 0.0f) ? tau_m : tau_lo;
        }
        float s = 0.0f;
        #pragma unroll
        for (int j = 0; j < 64; ++j) {
            const float pm = pgen(row[j] - tau_m, inv);
            row[j] = pm;
            s += pm;
        }
        inv_sum = 1.0f / s;
    }

    // ---- av: res[h][lane] = inv_sum * sum_j p[j] * v[h][j]  via fp16 dot2
    half2v p2[32];
    #pragma unroll
    for (int i = 0; i < 32; ++i) p2[i] = pk(row[2 * i], row[2 * i + 1]);

    float acc[8];
    #pragma unroll
    for (int h = 0; h < 8; ++h) {
        float a0 = 0.0f, a1 = 0.0f;
        #pragma unroll
        for (int jc = 0; jc < 8; ++jc) {
            union { half8 h8; half2v h2[4]; } u;
            u.h8 = *(const half8*)&v16[w][h * 32 + jc * 4];  // broadcast b128
            a0 = dot2(p2[jc * 4 + 0], u.h2[0], a0);
            a1 = dot2(p2[jc * 4 + 1], u.h2[1], a1);
            a0 = dot2(p2[jc * 4 + 2], u.h2[2], a0);
            a1 = dot2(p2[jc * 4 + 3], u.h2[3], a1);
        }
        acc[h] = a0 + a1;
    }
    float* rp = qb + (size_t)tok * HHE;   // res overwrites q (safe: own wave only)
    #pragma unroll
    for (int h = 0; h < 8; ++h) rp[h * 64 + lane] = acc[h] * inv_sum;
}

// ---------------------------------------------------------------------------
// Kernel 3: out = res @ Wu^T + bu   (M=16384, N=64, K=512)
// R5 version, unchanged (k-outer LDS GEMM, conflict-free). Held constant.
// ---------------------------------------------------------------------------
__global__ __launch_bounds__(256) void out_kernel(
    const float* __restrict__ resb, const float* __restrict__ Wu,
    const float* __restrict__ bu, float* __restrict__ out)
{
    __shared__ float rT[64 * 68];        // [kk][tok]  17.4 KB
    __shared__ float wT[64 * 68];        // [kk][m]    17.4 KB

    const int tid  = threadIdx.x;
    const int tok0 = blockIdx.x * 64;

    const int t    = tid >> 2;           // 0..63 (staging: token row / Wu row)
    const int kq2  = tid & 3;            // 0..3
    const int tokq = tid >> 4;           // 0..15 (compute: 4-token group)
    const int mq   = tid & 15;           // 0..15 (compute: 4-col group)

    float acc[4][4];
    #pragma unroll
    for (int a = 0; a < 4; ++a)
        #pragma unroll
        for (int b = 0; b < 4; ++b) acc[a][b] = 0.0f;

    const float4* rg = (const float4*)(resb + (size_t)(tok0 + t) * HHE);
    const float4* wg = (const float4*)(Wu   + (size_t)t * HHE);

    for (int kc = 0; kc < 8; ++kc) {
        // ---- stage res & Wu chunks transposed into LDS
        #pragma unroll
        for (int rep = 0; rep < 4; ++rep) {
            const int kq = rep * 4 + kq2;            // 0..15 within chunk
            const float4 rv = rg[kc * 16 + kq];
            rT[(kq * 4 + 0) * 68 + t] = rv.x;
            rT[(kq * 4 + 1) * 68 + t] = rv.y;
            rT[(kq * 4 + 2) * 68 + t] = rv.z;
            rT[(kq * 4 + 3) * 68 + t] = rv.w;
            const float4 wv = wg[kc * 16 + kq];
            wT[(kq * 4 + 0) * 68 + t] = wv.x;
            wT[(kq * 4 + 1) * 68 + t] = wv.y;
            wT[(kq * 4 + 2) * 68 + t] = wv.z;
            wT[(kq * 4 + 3) * 68 + t] = wv.w;
        }
        __syncthreads();

        // ---- compute: per kk, 2 x ds_read_b128 + 16 fma
        #pragma unroll 4
        for (int kk = 0; kk < 64; ++kk) {
            const float4 a4 = *(const float4*)&rT[kk * 68 + tokq * 4];
            const float4 b4 = *(const float4*)&wT[kk * 68 + mq * 4];
            const float ar[4] = {a4.x, a4.y, a4.z, a4.w};
            const float br[4] = {b4.x, b4.y, b4.z, b4.w};
            #pragma unroll
            for (int a = 0; a < 4; ++a)
                #pragma unroll
                for (int b = 0; b < 4; ++b)
                    acc[a][b] = fmaf(ar[a], br[b], acc[a][b]);
        }
        __syncthreads();                 // LDS reused next chunk
    }

    const float4 b4 = ((const float4*)bu)[mq];
    #pragma unroll
    for (int a = 0; a < 4; ++a) {
        float4 o;
        o.x = acc[a][0] + b4.x;
        o.y = acc[a][1] + b4.y;
        o.z = acc[a][2] + b4.z;
        o.w = acc[a][3] + b4.w;
        *(float4*)&out[(size_t)(tok0 + tokq * 4 + a) * 64 + mq * 4] = o;
    }
}

// ---------------------------------------------------------------------------
extern "C" void kernel_launch(void* const* d_in, const int* in_sizes, int n_in,
                              void* d_out, int out_size, void* d_ws, size_t ws_size,
                              hipStream_t stream)
{
    const float* x     = (const float*)d_in[0];
    const float* alpha = (const float*)d_in[1];
    const float* Wk    = (const float*)d_in[2];
    const float* bk    = (const float*)d_in[3];
    const float* Wq    = (const float*)d_in[4];
    const float* bq    = (const float*)d_in[5];
    const float* Wv    = (const float*)d_in[6];
    const float* bv    = (const float*)d_in[7];
    const float* Wu    = (const float*)d_in[8];
    const float* bu    = (const float*)d_in[9];
    float* out = (float*)d_out;

    float* ws = (float*)d_ws;
    float* qb = ws;                                  // res aliases q
    float* kb = ws + (size_t)NTOK * HHE;
    float* vb = ws + 2 * (size_t)NTOK * HHE;         // total 96 MB

    qkv_kernel<<<dim3(NTOK / 64, 4, 3), 256, 0, stream>>>(
        x, Wk, bk, Wq, bq, Wv, bv, qb, kb, vb);
    attn_kernel<<<NTOK / 4, 256, 0, stream>>>(qb, kb, vb, alpha);
    out_kernel<<<NTOK / 64, 256, 0, stream>>>(qb, Wu, bu, out);
}